// Round 2
// baseline (99.002 us; speedup 1.0000x reference)
//
#include <hip/hip_runtime.h>
#include <stdint.h>

#define BDIM 512
#define PDIM 512
#define T_   66
#define EMB  128
#define NS   24
#define NM   40
#define NI   70
#define CONT 32
#define OUTW 21408   // 32 + 66*128 + 66*128 + 70*64

typedef __attribute__((ext_vector_type(4))) float f32x4;
typedef __attribute__((ext_vector_type(8))) unsigned short u16x8;
typedef __attribute__((ext_vector_type(8))) __bf16 bf16x8;

static __device__ __forceinline__ unsigned short f2bf(float x) {
  union { float f; unsigned u; } v; v.f = x;
  unsigned r = (v.u + 0x7FFFu + ((v.u >> 16) & 1u)) >> 16;
  return (unsigned short)r;
}

static __device__ __forceinline__ f32x4 mfma16(u16x8 a, u16x8 b, f32x4 c) {
  return __builtin_amdgcn_mfma_f32_16x16x32_bf16(
      __builtin_bit_cast(bf16x8, a), __builtin_bit_cast(bf16x8, b), c, 0, 0, 0);
}

// ---------------------------------------------------------------------------
// Kernel 0: batch-independent precompute.
//  blocks 0..65 : both MLPs for t=blockIdx, 2-way split-K (quarter = tid>>7:
//                 bit0 = mlp, bit1 = k-half). Produces base_h (pre-relu) and
//                 base_out (full MLP with zero feats).
//  blocks 66/67 : Ws2 / Wm2 -> bf16 pre-swizzled into MFMA B-frag order:
//                 dst[((n*4+kk)*64+lane)*8+e] = W2[kk*32+(lane>>4)*8+e][n*16+(lane&15)]
// ---------------------------------------------------------------------------
__global__ __launch_bounds__(PDIM) void precomp(
    const float* __restrict__ char_emb,
    const float* __restrict__ Ws1, const float* __restrict__ bs1,
    const float* __restrict__ Ws2, const float* __restrict__ bs2,
    const float* __restrict__ Wm1, const float* __restrict__ bm1,
    const float* __restrict__ Wm2, const float* __restrict__ bm2,
    float* __restrict__ base_h_s, float* __restrict__ base_h_m,
    float* __restrict__ base_out_s, float* __restrict__ base_out_m,
    unsigned short* __restrict__ w2s_swz, unsigned short* __restrict__ w2m_swz) {
  const int bb = blockIdx.x, tid = threadIdx.x;
  if (bb < T_) {
    const int t = bb;
    const int quarter = tid >> 7;      // 0..3
    const int col = tid & 127;
    const int mlp = quarter & 1;       // 0 screen, 1 mini
    const int kh = quarter >> 1;       // k half
    const float* W1 = mlp ? Wm1 : Ws1;
    const float* W2 = mlp ? Wm2 : Ws2;
    const float* b1 = mlp ? bm1 : bs1;
    const float* b2 = mlp ? bm2 : bs2;
    float* bh = mlp ? base_h_m : base_h_s;
    float* bo = mlp ? base_out_m : base_out_s;
    __shared__ float part[4][EMB];
    __shared__ float h[2][EMB];
    float acc = 0.f;
#pragma unroll 8
    for (int f = kh * 64; f < kh * 64 + 64; ++f)
      acc += char_emb[t * EMB + f] * W1[f * EMB + col];
    part[quarter][col] = acc;
    __syncthreads();
    if (tid < 256) {
      const float v = b1[col] + part[mlp][col] + part[2 + mlp][col];
      bh[t * EMB + col] = v;           // pre-relu (needed for feat correction)
      h[mlp][col] = fmaxf(v, 0.f);
    }
    __syncthreads();
    float acc2 = 0.f;
#pragma unroll 8
    for (int i = kh * 64; i < kh * 64 + 64; ++i)
      acc2 += h[mlp][i] * W2[i * EMB + col];
    part[quarter][col] = acc2;
    __syncthreads();
    if (tid < 256)
      bo[t * EMB + col] = b2[col] + part[mlp][col] + part[2 + mlp][col];
  } else {
    const int mlp = bb - T_;
    const float* W2 = mlp ? Wm2 : Ws2;
    unsigned short* dst = mlp ? w2m_swz : w2s_swz;
    for (int idx = tid; idx < 8 * 4 * 64 * 8; idx += PDIM) {
      const int e = idx & 7, lane = (idx >> 3) & 63, kk = (idx >> 9) & 3, n = idx >> 11;
      const int k = kk * 32 + (lane >> 4) * 8 + e;
      const int col = n * 16 + (lane & 15);
      dst[idx] = f2bf(W2[k * EMB + col]);
    }
  }
}

// ---------------------------------------------------------------------------
// Kernel 1: one block per sample, 8 waves, 2 syncs, no output LDS staging.
//   wave w owns output col-tile n = w (cols [16n,16n+16)).
//   MFMA C-frag (col=lane&15, row=(lane>>4)*4+q) stored DIRECTLY to global:
//   each store_dword covers 4 rows x 64B aligned segments.
// ---------------------------------------------------------------------------
__global__ __launch_bounds__(BDIM) void fused(
    const float* __restrict__ contf,
    const float* __restrict__ sfeat,
    const float* __restrict__ mfeat,
    const float* __restrict__ item_emb,
    const float* __restrict__ Ws1,
    const float* __restrict__ bs2,
    const float* __restrict__ Wm1,
    const float* __restrict__ bm2,
    const int* __restrict__ sids,
    const int* __restrict__ mids,
    const int* __restrict__ items,
    const float* __restrict__ base_h_s, const float* __restrict__ base_h_m,
    const float* __restrict__ base_out_s, const float* __restrict__ base_out_m,
    const unsigned short* __restrict__ w2s_swz, const unsigned short* __restrict__ w2m_swz,
    float* __restrict__ out) {
  const int b = blockIdx.x, tid = threadIdx.x;

  __shared__ int s_map[T_], m_map[T_];
  __shared__ int s_id[NS], m_id[NM], s_item[NI];
  __shared__ float s_f[NS * 4], m_f[NM * 2];
  __shared__ u16x8 h_frag[5 * 4 * 64];      // bf16 A-fragments, 20 KB

  // ---- phase 1: stage ids/feats/items, init maps ----
  if (tid < T_) { s_map[tid] = -1; m_map[tid] = -1; }
  if (tid < NS) s_id[tid] = sids[b * NS + tid];
  if (tid < NM) m_id[tid] = mids[b * NM + tid];
  if (tid < NI) s_item[tid] = items[b * NI + tid];
  if (tid < NS * 4) s_f[tid] = sfeat[b * NS * 4 + tid];
  if (tid < NM * 2) m_f[tid] = mfeat[b * NM * 2 + tid];
  __syncthreads();

  // ---- phase 2: scatter maps + detection h -> bf16 A-fragment layout ----
  if (tid < NS) s_map[s_id[tid]] = tid;     // unique ids per sample
  if (tid < NM) m_map[m_id[tid]] = tid;
  for (int u = tid; u < 5 * 4 * 64; u += BDIM) {
    const int lane = u & 63, kk = (u >> 6) & 3, tile = u >> 8;
    const int g = lane >> 4, r = lane & 15;
    const int k0 = kk * 32 + g * 8;
    const bool scr = tile < 2;
    const int j = scr ? tile * 16 + r : (tile - 2) * 16 + r;
    const int nd = scr ? NS : NM;
    float v[8];
    if (j < nd) {
      const int t = scr ? s_id[j] : m_id[j];
      const float* bh = (scr ? base_h_s : base_h_m) + t * EMB + k0;
#pragma unroll
      for (int e = 0; e < 8; ++e) v[e] = bh[e];
      if (scr) {
        const float* fp = &s_f[j * 4];
#pragma unroll
        for (int c = 0; c < 4; ++c) {
          const float fc = fp[c];
          const float* wp = Ws1 + (128 + c) * EMB + k0;
#pragma unroll
          for (int e = 0; e < 8; ++e) v[e] += fc * wp[e];
        }
      } else {
        const float* fp = &m_f[j * 2];
#pragma unroll
        for (int c = 0; c < 2; ++c) {
          const float fc = fp[c];
          const float* wp = Wm1 + (128 + c) * EMB + k0;
#pragma unroll
          for (int e = 0; e < 8; ++e) v[e] += fc * wp[e];
        }
      }
#pragma unroll
      for (int e = 0; e < 8; ++e) v[e] = fmaxf(v[e], 0.f);
    } else {
#pragma unroll
      for (int e = 0; e < 8; ++e) v[e] = 0.f;  // pad rows: keep MFMA NaN-free
    }
    u16x8 pk;
#pragma unroll
    for (int e = 0; e < 8; ++e) pk[e] = f2bf(v[e]);
    h_frag[u] = pk;
  }
  __syncthreads();

  // ---- phase 3: everything else, no more syncs ----
  const int lane = tid & 63, w = tid >> 6;
  const int g = lane >> 4, r = lane & 15;
  const int n = w;                           // wave's col tile
  float* outS = out + (size_t)b * OUTW + CONT;
  float* outM = outS + T_ * EMB;

  // B-fragments + bias (L2-resident)
  u16x8 bS[4], bM[4];
#pragma unroll
  for (int kk = 0; kk < 4; ++kk) {
    bS[kk] = reinterpret_cast<const u16x8*>(w2s_swz)[(n * 4 + kk) * 64 + lane];
    bM[kk] = reinterpret_cast<const u16x8*>(w2m_swz)[(n * 4 + kk) * 64 + lane];
  }
  const float biasS = bs2[n * 16 + r];
  const float biasM = bm2[n * 16 + r];

  // screen detection GEMM -> direct scatter stores
#pragma unroll
  for (int m = 0; m < 2; ++m) {
    f32x4 acc = {biasS, biasS, biasS, biasS};
#pragma unroll
    for (int kk = 0; kk < 4; ++kk)
      acc = mfma16(h_frag[(m * 4 + kk) * 64 + lane], bS[kk], acc);
#pragma unroll
    for (int q = 0; q < 4; ++q) {
      const int rd = m * 16 + g * 4 + q;
      if (rd < NS) {
        const int t = s_id[rd];
        __builtin_nontemporal_store(acc[q], outS + t * EMB + n * 16 + r);
      }
    }
  }
  // minimap detection GEMM -> direct scatter stores
#pragma unroll
  for (int m = 0; m < 3; ++m) {
    f32x4 acc = {biasM, biasM, biasM, biasM};
#pragma unroll
    for (int kk = 0; kk < 4; ++kk)
      acc = mfma16(h_frag[((m + 2) * 4 + kk) * 64 + lane], bM[kk], acc);
#pragma unroll
    for (int q = 0; q < 4; ++q) {
      const int rd = m * 16 + g * 4 + q;
      if (rd < NM) {
        const int t = m_id[rd];
        __builtin_nontemporal_store(acc[q], outM + t * EMB + n * 16 + r);
      }
    }
  }

  // base (non-detection) rows: disjoint from det rows, no sync needed
  for (int u = tid; u < T_ * 32; u += BDIM) {
    const int t = u >> 5, q = u & 31;
    if (s_map[t] < 0) {
      const f32x4 v = reinterpret_cast<const f32x4*>(base_out_s + t * EMB)[q];
      __builtin_nontemporal_store(v, reinterpret_cast<f32x4*>(outS + t * EMB) + q);
    }
  }
  for (int u = tid; u < T_ * 32; u += BDIM) {
    const int t = u >> 5, q = u & 31;
    if (m_map[t] < 0) {
      const f32x4 v = reinterpret_cast<const f32x4*>(base_out_m + t * EMB)[q];
      __builtin_nontemporal_store(v, reinterpret_cast<f32x4*>(outM + t * EMB) + q);
    }
  }

  // continuous + item gather (pure copies, fp32 exact)
  {
    f32x4* ob = reinterpret_cast<f32x4*>(out + (size_t)b * OUTW);
    const f32x4* cb = reinterpret_cast<const f32x4*>(contf + (size_t)b * CONT);
    float* outI = out + (size_t)b * OUTW + (CONT + 2 * T_ * EMB);
    for (int u = tid; u < 8 + NI * 16; u += BDIM) {
      if (u < 8) {
        __builtin_nontemporal_store(cb[u], &ob[u]);
      } else {
        const int v2 = u - 8, j = v2 >> 4, q = v2 & 15;
        const int it = s_item[j];
        const f32x4 src = reinterpret_cast<const f32x4*>(item_emb + it * 64)[q];
        __builtin_nontemporal_store(src, reinterpret_cast<f32x4*>(outI + j * 64) + q);
      }
    }
  }
}

// ---------------------------------------------------------------------------
extern "C" void kernel_launch(void* const* d_in, const int* in_sizes, int n_in,
                              void* d_out, int out_size, void* d_ws, size_t ws_size,
                              hipStream_t stream) {
  const float* contf    = (const float*)d_in[0];
  const float* sfeat    = (const float*)d_in[1];
  const float* mfeat    = (const float*)d_in[2];
  const float* char_emb = (const float*)d_in[3];
  const float* item_emb = (const float*)d_in[4];
  const float* Ws1 = (const float*)d_in[5];
  const float* bs1 = (const float*)d_in[6];
  const float* Ws2 = (const float*)d_in[7];
  const float* bs2 = (const float*)d_in[8];
  const float* Wm1 = (const float*)d_in[9];
  const float* bm1 = (const float*)d_in[10];
  const float* Wm2 = (const float*)d_in[11];
  const float* bm2 = (const float*)d_in[12];
  const int* sids  = (const int*)d_in[13];
  const int* mids  = (const int*)d_in[14];
  const int* items = (const int*)d_in[15];
  float* out = (float*)d_out;

  const int B = in_sizes[0] / CONT;

  // workspace layout (bytes): 4x base tables (33792 each) + 2x bf16 W2 (32768 each)
  char* ws = (char*)d_ws;
  float* base_h_s   = (float*)(ws + 0);
  float* base_h_m   = (float*)(ws + 33792);
  float* base_out_s = (float*)(ws + 67584);
  float* base_out_m = (float*)(ws + 101376);
  unsigned short* w2s = (unsigned short*)(ws + 135168);
  unsigned short* w2m = (unsigned short*)(ws + 167936);

  precomp<<<T_ + 2, PDIM, 0, stream>>>(char_emb, Ws1, bs1, Ws2, bs2, Wm1, bm1, Wm2, bm2,
                                       base_h_s, base_h_m, base_out_s, base_out_m, w2s, w2m);
  fused<<<B, BDIM, 0, stream>>>(contf, sfeat, mfeat, item_emb, Ws1, bs2, Wm1, bm2,
                                sids, mids, items,
                                base_h_s, base_h_m, base_out_s, base_out_m, w2s, w2m, out);
}